// Round 1
// 339.688 us; speedup vs baseline: 1.1786x; 1.1786x over previous
//
#include <hip/hip_runtime.h>
#include <hip/hip_bf16.h>

// Problem constants
#define EDIM 1024
#define TDIM 2048
#define MTOT 32768   // B*T = 16*2048

typedef __attribute__((ext_vector_type(8))) short short8;
typedef __attribute__((ext_vector_type(8))) unsigned short ushort8;
typedef __attribute__((ext_vector_type(4))) float f32x4;

__device__ __forceinline__ ushort f2bf(float f) {
  unsigned u = __float_as_uint(f);
  u += 0x7fff + ((u >> 16) & 1);   // RNE
  return (ushort)(u >> 16);
}

// global -> LDS direct DMA, 16B per lane. LDS dest is wave-uniform base +
// lane*16 (guide m104/m108); global src is per-lane.
__device__ __forceinline__ void gld16(const void* g, void* l) {
  __builtin_amdgcn_global_load_lds(
      (const __attribute__((address_space(1))) void*)g,
      (__attribute__((address_space(3))) void*)l, 16, 0, 0);
}

// ---------------------------------------------------------------------------
// K0: Psum[c][e] = sum_h pos_w[h,e,c]  (f32 inputs). 12x256 = 3072 threads.
// ---------------------------------------------------------------------------
__global__ __launch_bounds__(256) void prep_kernel(
    const float* __restrict__ pos_w, float* __restrict__ Psum) {
  int idx = blockIdx.x * 256 + threadIdx.x;       // 0..3071
  int c = idx >> 10, e = idx & 1023;
  float s = 0.f;
#pragma unroll
  for (int h = 0; h < 8; ++h) s += pos_w[h * (EDIM * 3) + e * 3 + c];
  Psum[idx] = s;                                  // layout Psum[c*1024 + e]
}

// ---------------------------------------------------------------------------
// K0b: one-time f32 -> bf16 convert of ffn_w (1M elems). Removes the per-block
// redundant f2bf VALU work from the GEMM (each W panel was converted 256x).
// ---------------------------------------------------------------------------
__global__ __launch_bounds__(256) void wcvt_kernel(
    const float* __restrict__ W, ushort* __restrict__ Wb) {
  int i = (blockIdx.x * 256 + threadIdx.x) << 2;
  float4 v = *(const float4*)&W[i];
  ushort4 o;
  o.x = f2bf(v.x); o.y = f2bf(v.y); o.z = f2bf(v.z); o.w = f2bf(v.w);
  *(ushort4*)&Wb[i] = o;
}

// ---------------------------------------------------------------------------
// K1: mid[m,e] = (1/24) * sum_c s_c * win_c[e];  s_c = <win_c, Psum[c]>
//     win_c = embed_table[tokens[m-2+c]] (f32), zeros when t-2+c < 0.
// One block per token m; 256 threads x 4 elems. Writes bf16 mid into ws.
// ---------------------------------------------------------------------------
__global__ __launch_bounds__(256) void mid_kernel(
    const int* __restrict__ tokens, const float* __restrict__ embed,
    const float* __restrict__ Psum, ushort* __restrict__ mid) {
  int m = blockIdx.x;
  int t = m & (TDIM - 1);
  int tid = threadIdx.x;
  int e4 = tid << 2;

  float4 r0 = make_float4(0.f, 0.f, 0.f, 0.f), r1 = r0, r2;
  float p0 = 0.f, p1 = 0.f, p2;

  if (t >= 2) {
    r0 = *(const float4*)&embed[(size_t)tokens[m - 2] * EDIM + e4];
    float4 ps = *(const float4*)&Psum[0 * EDIM + e4];
    p0 = r0.x * ps.x + r0.y * ps.y + r0.z * ps.z + r0.w * ps.w;
  }
  if (t >= 1) {
    r1 = *(const float4*)&embed[(size_t)tokens[m - 1] * EDIM + e4];
    float4 ps = *(const float4*)&Psum[1 * EDIM + e4];
    p1 = r1.x * ps.x + r1.y * ps.y + r1.z * ps.z + r1.w * ps.w;
  }
  {
    r2 = *(const float4*)&embed[(size_t)tokens[m] * EDIM + e4];
    float4 ps = *(const float4*)&Psum[2 * EDIM + e4];
    p2 = r2.x * ps.x + r2.y * ps.y + r2.z * ps.z + r2.w * ps.w;
  }

#pragma unroll
  for (int off = 32; off; off >>= 1) {
    p0 += __shfl_xor(p0, off);
    p1 += __shfl_xor(p1, off);
    p2 += __shfl_xor(p2, off);
  }
  __shared__ float red[4][3];
  int wv = tid >> 6, ln = tid & 63;
  if (ln == 0) { red[wv][0] = p0; red[wv][1] = p1; red[wv][2] = p2; }
  __syncthreads();
  float s0 = (red[0][0] + red[1][0]) + (red[2][0] + red[3][0]);
  float s1 = (red[0][1] + red[1][1]) + (red[2][1] + red[3][1]);
  float s2 = (red[0][2] + red[1][2]) + (red[2][2] + red[3][2]);

  const float inv = 1.0f / 24.0f;
  ushort4 o;
  o.x = f2bf((s0 * r0.x + s1 * r1.x + s2 * r2.x) * inv);
  o.y = f2bf((s0 * r0.y + s1 * r1.y + s2 * r2.y) * inv);
  o.z = f2bf((s0 * r0.z + s1 * r1.z + s2 * r2.z) * inv);
  o.w = f2bf((s0 * r0.w + s1 * r1.w + s2 * r2.w) * inv);
  *(ushort4*)&mid[(size_t)m * EDIM + e4] = o;
}

// ---------------------------------------------------------------------------
// K2: y[m,n] = sum_k mid[m,k]*W[n,k] + bias[n]   (gemm_bt, bf16 MFMA)
// m97 structure [guide §5 ladder step 3, 874-912 TF at 128^2]:
//   - both operands bf16 in global (A = mid from ws, B = Wb pre-converted)
//   - staging via global_load_lds dwordx4 (no VGPR round-trip, no ds_write)
//   - 128x128 tile, BK=32, 4 waves each 64x64 (4x4 of 16x16x32)
//   - XCD-chunked block swizzle: nwg=2048 %8==0 -> bijective (guide T1);
//     each XCD owns 32 consecutive M-panels x all 8 N-tiles, so an A-panel
//     (256 KB) is fetched once per XCD L2 instead of 8x from HBM.
// A-frag: A[m=lane&15][k=(lane>>4)*8+j]; C/D: col=lane&15, row=(lane>>4)*4+reg
// [guide §3, measured m89/m91/m97].
// LDS staging map (linear dest, required by global_load_lds):
//   wave w stages As rows [w*32, w*32+32) as two 1024B chunks (16 rows of
//   64B each); lane l covers row base+(l>>2), col elems (l&3)*8.
// ---------------------------------------------------------------------------
__global__ __launch_bounds__(256) void gemm_kernel(
    const ushort* __restrict__ A, const ushort* __restrict__ Wb,
    const float* __restrict__ bias, float* __restrict__ out) {
  __shared__ ushort As[128 * 32];
  __shared__ ushort Bs[128 * 32];
  int tid = threadIdx.x;
  int wave = tid >> 6, lane = tid & 63;

  // XCD-chunked swizzle (nwg = 2048, divisible by 8 -> bijective)
  int linear = (blockIdx.y << 3) | blockIdx.x;
  int swz = ((linear & 7) << 8) | (linear >> 3);
  int tileM = (swz >> 3) << 7;
  int tileN = (swz & 7) << 7;

  int wm = (wave >> 1) << 6;
  int wn = (wave & 1) << 6;

  f32x4 acc[4][4];
#pragma unroll
  for (int i = 0; i < 4; ++i)
#pragma unroll
    for (int j = 0; j < 4; ++j) acc[i][j] = (f32x4){0.f, 0.f, 0.f, 0.f};

  // staging addresses
  int sr = lane >> 2;            // 0..15 row within chunk
  int sc = (lane & 3) << 3;      // elem col 0,8,16,24
  const ushort* Ap = A  + (size_t)(tileM + (wave << 5) + sr) * EDIM + sc;
  const ushort* Bp = Wb + (size_t)(tileN + (wave << 5) + sr) * EDIM + sc;
  ushort* aDst = &As[(wave << 1) * 512];   // 1024B chunk base (wave-uniform)
  ushort* bDst = &Bs[(wave << 1) * 512];

  int arow = lane & 15;
  int kq = (lane >> 4) << 3;

  for (int k0 = 0; k0 < EDIM; k0 += 32) {
    gld16(Ap + k0, aDst);
    gld16(Ap + (size_t)16 * EDIM + k0, aDst + 512);
    gld16(Bp + k0, bDst);
    gld16(Bp + (size_t)16 * EDIM + k0, bDst + 512);
    __syncthreads();   // compiler emits s_waitcnt vmcnt(0) lgkmcnt(0) first

    short8 af[4], bfv[4];
#pragma unroll
    for (int i = 0; i < 4; ++i) {
      af[i]  = *(const short8*)&As[(wm + i * 16 + arow) * 32 + kq];
      bfv[i] = *(const short8*)&Bs[(wn + i * 16 + arow) * 32 + kq];
    }
#pragma unroll
    for (int i = 0; i < 4; ++i)
#pragma unroll
      for (int j = 0; j < 4; ++j)
        acc[i][j] = __builtin_amdgcn_mfma_f32_16x16x32_bf16(af[i], bfv[j], acc[i][j], 0, 0, 0);
    __syncthreads();
  }

  int col0 = lane & 15, rq = (lane >> 4) << 2;
#pragma unroll
  for (int j = 0; j < 4; ++j) {
    int col = tileN + wn + j * 16 + col0;
    float bv = bias[col];
#pragma unroll
    for (int i = 0; i < 4; ++i) {
      int row = tileM + wm + i * 16 + rq;
#pragma unroll
      for (int r = 0; r < 4; ++r)
        out[(size_t)(row + r) * EDIM + col] = acc[i][j][r] + bv;   // f32 store
    }
  }
}

// ---------------------------------------------------------------------------
// K3: LayerNorm + swish, IN-PLACE f32 on d_out. Block = one row of 1024.
// Per-row in-place: block m reads and writes only bytes [4096m, 4096m+4096).
// ---------------------------------------------------------------------------
__global__ __launch_bounds__(256) void ln_kernel(
    float* __restrict__ y, const float* __restrict__ g,
    const float* __restrict__ bta) {
  int m = blockIdx.x, tid = threadIdx.x;
  int e4 = tid << 2;
  float4 v = *(const float4*)&y[(size_t)m * EDIM + e4];
  float s = (v.x + v.y) + (v.z + v.w);
  float q = (v.x * v.x + v.y * v.y) + (v.z * v.z + v.w * v.w);
#pragma unroll
  for (int off = 32; off; off >>= 1) {
    s += __shfl_xor(s, off);
    q += __shfl_xor(q, off);
  }
  __shared__ float red[4][2];
  int wv = tid >> 6, ln = tid & 63;
  if (ln == 0) { red[wv][0] = s; red[wv][1] = q; }
  __syncthreads();
  float S = (red[0][0] + red[1][0]) + (red[2][0] + red[3][0]);
  float Q = (red[0][1] + red[1][1]) + (red[2][1] + red[3][1]);
  float mu = S * (1.0f / EDIM);
  float var = Q * (1.0f / EDIM) - mu * mu;
  float rs = rsqrtf(var + 1e-5f);
  float4 gg = *(const float4*)&g[e4];
  float4 bb = *(const float4*)&bta[e4];
  float x0 = (v.x - mu) * rs * gg.x + bb.x;
  float x1 = (v.y - mu) * rs * gg.y + bb.y;
  float x2 = (v.z - mu) * rs * gg.z + bb.z;
  float x3 = (v.w - mu) * rs * gg.w + bb.w;
  float4 o;
  o.x = x0 / (1.f + expf(-x0));
  o.y = x1 / (1.f + expf(-x1));
  o.z = x2 / (1.f + expf(-x2));
  o.w = x3 / (1.f + expf(-x3));
  *(float4*)&y[(size_t)m * EDIM + e4] = o;
}

// ---------------------------------------------------------------------------
// Buffer plan (ws usage = 64 MiB + 16 KiB + 2 MiB):
//   ws[0 : 64 MiB)                      mid   (bf16; mid_kernel -> gemm)
//   ws[64 MiB : 64 MiB + 12 KiB)        Psum  (prep -> mid)
//   ws[64 MiB + 16 KiB : + 2 MiB)       Wb    (bf16 ffn_w; wcvt -> gemm)
//   d_out (f32, 128 MB)                 y     (gemm, f32) -> final (ln in-place)
// Inputs are f32 (round-4 NaN proved bf16-reading is wrong); OUTPUT IS F32
// per harness doc (reference output dtype = float32).
// ---------------------------------------------------------------------------
extern "C" void kernel_launch(void* const* d_in, const int* in_sizes, int n_in,
                              void* d_out, int out_size, void* d_ws, size_t ws_size,
                              hipStream_t stream) {
  const int*   tokens = (const int*)d_in[0];
  const float* embed  = (const float*)d_in[1];
  const float* pos_w  = (const float*)d_in[2];
  const float* ffn_w  = (const float*)d_in[3];
  const float* ffn_b  = (const float*)d_in[4];
  const float* ln_g   = (const float*)d_in[5];
  const float* ln_b   = (const float*)d_in[6];

  char* ws = (char*)d_ws;
  float*  outp = (float*)d_out;                              // f32 output!
  ushort* midw = (ushort*)ws;                                // 64 MiB bf16
  float*  Psum = (float*)(ws + (size_t)64 * 1024 * 1024);    // 12 KiB
  ushort* Wb   = (ushort*)(ws + (size_t)64 * 1024 * 1024 + 16 * 1024);  // 2 MiB

  prep_kernel<<<12, 256, 0, stream>>>(pos_w, Psum);
  wcvt_kernel<<<1024, 256, 0, stream>>>(ffn_w, Wb);
  mid_kernel<<<MTOT, 256, 0, stream>>>(tokens, embed, Psum, midw);
  dim3 g2(8, 256);
  gemm_kernel<<<g2, 256, 0, stream>>>(midw, Wb, ffn_b, outp);
  ln_kernel<<<MTOT, 256, 0, stream>>>(outp, ln_g, ln_b);
}

// Round 2
// 258.315 us; speedup vs baseline: 1.5499x; 1.3150x over previous
//
#include <hip/hip_runtime.h>
#include <hip/hip_bf16.h>

// Problem constants
#define EDIM 1024
#define TDIM 2048
#define MTOT 32768   // B*T = 16*2048
#define VCAP 8192    // vocab 8000 padded to 8192 for 128-row GEMM tiles

typedef __attribute__((ext_vector_type(8))) short short8;
typedef __attribute__((ext_vector_type(8))) unsigned short ushort8;
typedef __attribute__((ext_vector_type(4))) float f32x4;

__device__ __forceinline__ ushort f2bf(float f) {
  unsigned u = __float_as_uint(f);
  u += 0x7fff + ((u >> 16) & 1);   // RNE
  return (ushort)(u >> 16);
}

// global -> LDS direct DMA, 16B per lane. LDS dest is wave-uniform base +
// lane*16 (guide m104/m108); global src is per-lane.
__device__ __forceinline__ void gld16(const void* g, void* l) {
  __builtin_amdgcn_global_load_lds(
      (const __attribute__((address_space(1))) void*)g,
      (__attribute__((address_space(3))) void*)l, 16, 0, 0);
}

// ---------------------------------------------------------------------------
// Algebraic plan (round 2 restructure):
//   mid[m]      = (1/24) * sum_c s_c(m) * embed[tok_c],  s_c = <embed[tok_c], Psum_c>
//   y[m]        = mid[m] @ W^T + b = (1/24) * sum_c s_c * EW[tok_c] + b
//   where EW[v] = embed[v] @ W^T  (vocab-sized GEMM: 8000 rows, not 32768!)
//   out[m]      = swish(LN(y[m]))
// Pipeline: prep(Psum) -> wcvt(Wb) -> dcvt(Ebf,D) -> gemm(EW) -> final(out)
// ---------------------------------------------------------------------------

// ---------------------------------------------------------------------------
// K0: Psum[c][e] = sum_h pos_w[h,e,c]  (f32 inputs). 12x256 = 3072 threads.
// ---------------------------------------------------------------------------
__global__ __launch_bounds__(256) void prep_kernel(
    const float* __restrict__ pos_w, float* __restrict__ Psum) {
  int idx = blockIdx.x * 256 + threadIdx.x;       // 0..3071
  int c = idx >> 10, e = idx & 1023;
  float s = 0.f;
#pragma unroll
  for (int h = 0; h < 8; ++h) s += pos_w[h * (EDIM * 3) + e * 3 + c];
  Psum[idx] = s;                                  // layout Psum[c*1024 + e]
}

// ---------------------------------------------------------------------------
// K0b: one-time f32 -> bf16 convert of ffn_w (1M elems).
// ---------------------------------------------------------------------------
__global__ __launch_bounds__(256) void wcvt_kernel(
    const float* __restrict__ W, ushort* __restrict__ Wb) {
  int i = (blockIdx.x * 256 + threadIdx.x) << 2;
  float4 v = *(const float4*)&W[i];
  ushort4 o;
  o.x = f2bf(v.x); o.y = f2bf(v.y); o.z = f2bf(v.z); o.w = f2bf(v.w);
  *(ushort4*)&Wb[i] = o;
}

// ---------------------------------------------------------------------------
// K1: per vocab row v: Ebf[v] = bf16(embed[v]);  D[v][c] = <embed[v], Psum_c>.
// One block per row, 256 threads x 4 elems. Rows >= 8000 zeroed (GEMM padding;
// never gathered since tokens < 8000).
// ---------------------------------------------------------------------------
__global__ __launch_bounds__(256) void dcvt_kernel(
    const float* __restrict__ embed, const float* __restrict__ Psum,
    ushort* __restrict__ Ebf, float* __restrict__ D) {
  int v = blockIdx.x;                  // 0..8191
  int tid = threadIdx.x;
  int e4 = tid << 2;
  if (v >= 8000) {
    ushort4 z; z.x = z.y = z.z = z.w = 0;
    *(ushort4*)&Ebf[(size_t)v * EDIM + e4] = z;
    if (tid < 4) D[v * 4 + tid] = 0.f;
    return;
  }
  float4 r = *(const float4*)&embed[(size_t)v * EDIM + e4];
  ushort4 o;
  o.x = f2bf(r.x); o.y = f2bf(r.y); o.z = f2bf(r.z); o.w = f2bf(r.w);
  *(ushort4*)&Ebf[(size_t)v * EDIM + e4] = o;

  float4 q0 = *(const float4*)&Psum[0 * EDIM + e4];
  float4 q1 = *(const float4*)&Psum[1 * EDIM + e4];
  float4 q2 = *(const float4*)&Psum[2 * EDIM + e4];
  float p0 = r.x * q0.x + r.y * q0.y + r.z * q0.z + r.w * q0.w;
  float p1 = r.x * q1.x + r.y * q1.y + r.z * q1.z + r.w * q1.w;
  float p2 = r.x * q2.x + r.y * q2.y + r.z * q2.z + r.w * q2.w;
#pragma unroll
  for (int off = 32; off; off >>= 1) {
    p0 += __shfl_xor(p0, off);
    p1 += __shfl_xor(p1, off);
    p2 += __shfl_xor(p2, off);
  }
  __shared__ float red[4][3];
  int wv = tid >> 6, ln = tid & 63;
  if (ln == 0) { red[wv][0] = p0; red[wv][1] = p1; red[wv][2] = p2; }
  __syncthreads();
  if (tid < 3) {
    D[v * 4 + tid] = (red[0][tid] + red[1][tid]) + (red[2][tid] + red[3][tid]);
  }
}

// ---------------------------------------------------------------------------
// K2: EW[v,n] = sum_k Ebf[v,k]*Wb[n,k]   (gemm_bt, bf16 MFMA, f32 out, NO bias)
// m97 structure [guide §5 step 3]: global_load_lds dwordx4 staging, 128x128
// tile, BK=32, 4 waves each 64x64 (4x4 of 16x16x32). M=8192 -> grid (8,64),
// nwg=512 %8==0 -> bijective XCD-chunked swizzle (CPX=64).
// A-frag: A[m=lane&15][k=(lane>>4)*8+j]; C/D: col=lane&15, row=(lane>>4)*4+reg
// [guide §3, measured m89/m91/m97].
// ---------------------------------------------------------------------------
__global__ __launch_bounds__(256) void gemm_kernel(
    const ushort* __restrict__ A, const ushort* __restrict__ Wb,
    float* __restrict__ out) {
  __shared__ ushort As[128 * 32];
  __shared__ ushort Bs[128 * 32];
  int tid = threadIdx.x;
  int wave = tid >> 6, lane = tid & 63;

  // XCD-chunked swizzle (nwg = 512, divisible by 8 -> bijective; CPX = 64)
  int linear = (blockIdx.y << 3) | blockIdx.x;
  int swz = ((linear & 7) << 6) | (linear >> 3);
  int tileM = (swz >> 3) << 7;
  int tileN = (swz & 7) << 7;

  int wm = (wave >> 1) << 6;
  int wn = (wave & 1) << 6;

  f32x4 acc[4][4];
#pragma unroll
  for (int i = 0; i < 4; ++i)
#pragma unroll
    for (int j = 0; j < 4; ++j) acc[i][j] = (f32x4){0.f, 0.f, 0.f, 0.f};

  // staging addresses: wave w stages 32 rows of each operand as 2x1024B chunks
  int sr = lane >> 2;            // 0..15 row within chunk
  int sc = (lane & 3) << 3;      // elem col 0,8,16,24
  const ushort* Ap = A  + (size_t)(tileM + (wave << 5) + sr) * EDIM + sc;
  const ushort* Bp = Wb + (size_t)(tileN + (wave << 5) + sr) * EDIM + sc;
  ushort* aDst = &As[(wave << 1) * 512];   // 1024B chunk base (wave-uniform)
  ushort* bDst = &Bs[(wave << 1) * 512];

  int arow = lane & 15;
  int kq = (lane >> 4) << 3;

  for (int k0 = 0; k0 < EDIM; k0 += 32) {
    gld16(Ap + k0, aDst);
    gld16(Ap + (size_t)16 * EDIM + k0, aDst + 512);
    gld16(Bp + k0, bDst);
    gld16(Bp + (size_t)16 * EDIM + k0, bDst + 512);
    __syncthreads();   // compiler emits s_waitcnt vmcnt(0) lgkmcnt(0) first

    short8 af[4], bfv[4];
#pragma unroll
    for (int i = 0; i < 4; ++i) {
      af[i]  = *(const short8*)&As[(wm + i * 16 + arow) * 32 + kq];
      bfv[i] = *(const short8*)&Bs[(wn + i * 16 + arow) * 32 + kq];
    }
#pragma unroll
    for (int i = 0; i < 4; ++i)
#pragma unroll
      for (int j = 0; j < 4; ++j)
        acc[i][j] = __builtin_amdgcn_mfma_f32_16x16x32_bf16(af[i], bfv[j], acc[i][j], 0, 0, 0);
    __syncthreads();
  }

  int col0 = lane & 15, rq = (lane >> 4) << 2;
#pragma unroll
  for (int j = 0; j < 4; ++j) {
    int col = tileN + wn + j * 16 + col0;
#pragma unroll
    for (int i = 0; i < 4; ++i) {
      int row = tileM + wm + i * 16 + rq;
#pragma unroll
      for (int r = 0; r < 4; ++r)
        out[(size_t)(row + r) * EDIM + col] = acc[i][j][r];   // f32 store
    }
  }
}

// ---------------------------------------------------------------------------
// K3: final fused kernel. Block = one token m (256 threads x 4 elems).
//   y = (s0*EW[i0] + s1*EW[i1] + s2*EW[i2])/24 + bias;  out = swish(LN(y)).
// s_c are scalar lookups into D (per token-id). EW (32 MB) is L3-resident.
// Window boundary: t==0 -> only c=2; t==1 -> c=1,2 (zeroed coefficients).
// ---------------------------------------------------------------------------
__global__ __launch_bounds__(256) void final_kernel(
    const int* __restrict__ tokens, const float* __restrict__ EW,
    const float* __restrict__ D, const float* __restrict__ bias,
    const float* __restrict__ g, const float* __restrict__ bta,
    float* __restrict__ out) {
  int m = blockIdx.x, tid = threadIdx.x;
  int t = m & (TDIM - 1);
  int e4 = tid << 2;

  int i2 = tokens[m];
  int i1 = (t >= 1) ? tokens[m - 1] : 0;
  int i0 = (t >= 2) ? tokens[m - 2] : 0;
  const float inv = 1.0f / 24.0f;
  float s2 = D[i2 * 4 + 2] * inv;
  float s1 = (t >= 1) ? D[i1 * 4 + 1] * inv : 0.f;
  float s0 = (t >= 2) ? D[i0 * 4 + 0] * inv : 0.f;

  float4 a0 = *(const float4*)&EW[(size_t)i0 * EDIM + e4];
  float4 a1 = *(const float4*)&EW[(size_t)i1 * EDIM + e4];
  float4 a2 = *(const float4*)&EW[(size_t)i2 * EDIM + e4];
  float4 bb = *(const float4*)&bias[e4];

  float x0 = s0 * a0.x + s1 * a1.x + s2 * a2.x + bb.x;
  float x1 = s0 * a0.y + s1 * a1.y + s2 * a2.y + bb.y;
  float x2 = s0 * a0.z + s1 * a1.z + s2 * a2.z + bb.z;
  float x3 = s0 * a0.w + s1 * a1.w + s2 * a2.w + bb.w;

  float s = (x0 + x1) + (x2 + x3);
  float q = (x0 * x0 + x1 * x1) + (x2 * x2 + x3 * x3);
#pragma unroll
  for (int off = 32; off; off >>= 1) {
    s += __shfl_xor(s, off);
    q += __shfl_xor(q, off);
  }
  __shared__ float red[4][2];
  int wv = tid >> 6, ln = tid & 63;
  if (ln == 0) { red[wv][0] = s; red[wv][1] = q; }
  __syncthreads();
  float S = (red[0][0] + red[1][0]) + (red[2][0] + red[3][0]);
  float Q = (red[0][1] + red[1][1]) + (red[2][1] + red[3][1]);
  float mu = S * (1.0f / EDIM);
  float var = Q * (1.0f / EDIM) - mu * mu;
  float rs = rsqrtf(var + 1e-5f);

  float4 gg = *(const float4*)&g[e4];
  float4 b2 = *(const float4*)&bta[e4];
  float y0 = (x0 - mu) * rs * gg.x + b2.x;
  float y1 = (x1 - mu) * rs * gg.y + b2.y;
  float y2 = (x2 - mu) * rs * gg.z + b2.z;
  float y3 = (x3 - mu) * rs * gg.w + b2.w;
  float4 o;
  o.x = y0 / (1.f + expf(-y0));
  o.y = y1 / (1.f + expf(-y1));
  o.z = y2 / (1.f + expf(-y2));
  o.w = y3 / (1.f + expf(-y3));
  *(float4*)&out[(size_t)m * EDIM + e4] = o;
}

// ---------------------------------------------------------------------------
// Buffer plan (ws usage < 51 MiB):
//   ws[ 0M : 16M)        Ebf   bf16 embed, 8192x1024 (dcvt -> gemm)
//   ws[16M : 48M)        EW    f32 embed@W^T, 8192x1024 (gemm -> final)
//   ws[48M : 50M)        Wb    bf16 ffn_w (wcvt -> gemm)
//   ws[50M : 50M+12K)    Psum  (prep -> dcvt)
//   ws[50M+16K : +128K)  D     f32 [8192][4] (dcvt -> final)
// OUTPUT IS F32 (reference output dtype = float32).
// ---------------------------------------------------------------------------
extern "C" void kernel_launch(void* const* d_in, const int* in_sizes, int n_in,
                              void* d_out, int out_size, void* d_ws, size_t ws_size,
                              hipStream_t stream) {
  const int*   tokens = (const int*)d_in[0];
  const float* embed  = (const float*)d_in[1];
  const float* pos_w  = (const float*)d_in[2];
  const float* ffn_w  = (const float*)d_in[3];
  const float* ffn_b  = (const float*)d_in[4];
  const float* ln_g   = (const float*)d_in[5];
  const float* ln_b   = (const float*)d_in[6];

  char* ws = (char*)d_ws;
  const size_t MB = 1024 * 1024;
  ushort* Ebf  = (ushort*)ws;                          // 16 MiB
  float*  EW   = (float*)(ws + 16 * MB);               // 32 MiB
  ushort* Wb   = (ushort*)(ws + 48 * MB);              // 2 MiB
  float*  Psum = (float*)(ws + 50 * MB);               // 12 KiB
  float*  D    = (float*)(ws + 50 * MB + 16 * 1024);   // 128 KiB
  float*  outp = (float*)d_out;                        // f32 output

  prep_kernel<<<12, 256, 0, stream>>>(pos_w, Psum);
  wcvt_kernel<<<1024, 256, 0, stream>>>(ffn_w, Wb);
  dcvt_kernel<<<VCAP, 256, 0, stream>>>(embed, Psum, Ebf, D);
  dim3 g2(8, 64);
  gemm_kernel<<<g2, 256, 0, stream>>>(Ebf, Wb, EW);
  final_kernel<<<MTOT, 256, 0, stream>>>(tokens, EW, D, ffn_b, ln_g, ln_b, outp);
}

// Round 3
// 231.782 us; speedup vs baseline: 1.7273x; 1.1145x over previous
//
#include <hip/hip_runtime.h>
#include <hip/hip_bf16.h>

// Problem constants
#define EDIM 1024
#define TDIM 2048
#define MTOT 32768   // B*T = 16*2048
#define VCAP 8192    // vocab 8000 padded to 8192 for 128-row GEMM tiles

typedef __attribute__((ext_vector_type(8))) short short8;
typedef __attribute__((ext_vector_type(8))) unsigned short ushort8;
typedef __attribute__((ext_vector_type(4))) float f32x4;

__device__ __forceinline__ ushort f2bf(float f) {
  unsigned u = __float_as_uint(f);
  u += 0x7fff + ((u >> 16) & 1);   // RNE
  return (ushort)(u >> 16);
}

// global -> LDS direct DMA, 16B per lane. LDS dest is wave-uniform base +
// lane*16 (guide m104/m108); global src is per-lane.
__device__ __forceinline__ void gld16(const void* g, void* l) {
  __builtin_amdgcn_global_load_lds(
      (const __attribute__((address_space(1))) void*)g,
      (__attribute__((address_space(3))) void*)l, 16, 0, 0);
}

// ---------------------------------------------------------------------------
// Algebraic plan:
//   mid[m] = (1/24) * sum_c s_c(m) * embed[tok_c],  s_c = <embed[tok_c], Psum_c>
//   y[m]   = (1/24) * sum_c s_c * EW[tok_c] + b,    EW[v] = embed[v] @ W^T
//   out[m] = swish(LN(y[m]))
// Pipeline: prep(Psum,Wb) -> dcvt(Ebf,D) -> gemm(EW) -> final(out)
// ---------------------------------------------------------------------------

// ---------------------------------------------------------------------------
// K0: merged prep. Blocks 0..1023: Wb = bf16(ffn_w) (1M elems).
//     Blocks 1024..1035: Psum[c][e] = sum_h pos_w[h,e,c].
// (independent jobs; merged to cut one launch from the graph)
// ---------------------------------------------------------------------------
__global__ __launch_bounds__(256) void prep_kernel(
    const float* __restrict__ pos_w, const float* __restrict__ W,
    float* __restrict__ Psum, ushort* __restrict__ Wb) {
  int b = blockIdx.x;
  if (b < 1024) {
    int i = (b * 256 + threadIdx.x) << 2;
    float4 v = *(const float4*)&W[i];
    ushort4 o;
    o.x = f2bf(v.x); o.y = f2bf(v.y); o.z = f2bf(v.z); o.w = f2bf(v.w);
    *(ushort4*)&Wb[i] = o;
  } else {
    int idx = (b - 1024) * 256 + threadIdx.x;     // 0..3071
    int c = idx >> 10, e = idx & 1023;
    float s = 0.f;
#pragma unroll
    for (int h = 0; h < 8; ++h) s += pos_w[h * (EDIM * 3) + e * 3 + c];
    Psum[idx] = s;                                // layout Psum[c*1024 + e]
  }
}

// ---------------------------------------------------------------------------
// K1: per vocab row v: Ebf[v] = bf16(embed[v]);  D[v][c] = <embed[v], Psum_c>.
// One block per row, 256 threads x 4 elems. Rows >= 8000 zeroed (GEMM padding;
// never gathered since tokens < 8000).
// ---------------------------------------------------------------------------
__global__ __launch_bounds__(256) void dcvt_kernel(
    const float* __restrict__ embed, const float* __restrict__ Psum,
    ushort* __restrict__ Ebf, float* __restrict__ D) {
  int v = blockIdx.x;                  // 0..8191
  int tid = threadIdx.x;
  int e4 = tid << 2;
  if (v >= 8000) {
    ushort4 z; z.x = z.y = z.z = z.w = 0;
    *(ushort4*)&Ebf[(size_t)v * EDIM + e4] = z;
    if (tid < 4) D[v * 4 + tid] = 0.f;
    return;
  }
  float4 r = *(const float4*)&embed[(size_t)v * EDIM + e4];
  ushort4 o;
  o.x = f2bf(r.x); o.y = f2bf(r.y); o.z = f2bf(r.z); o.w = f2bf(r.w);
  *(ushort4*)&Ebf[(size_t)v * EDIM + e4] = o;

  float4 q0 = *(const float4*)&Psum[0 * EDIM + e4];
  float4 q1 = *(const float4*)&Psum[1 * EDIM + e4];
  float4 q2 = *(const float4*)&Psum[2 * EDIM + e4];
  float p0 = r.x * q0.x + r.y * q0.y + r.z * q0.z + r.w * q0.w;
  float p1 = r.x * q1.x + r.y * q1.y + r.z * q1.z + r.w * q1.w;
  float p2 = r.x * q2.x + r.y * q2.y + r.z * q2.z + r.w * q2.w;
#pragma unroll
  for (int off = 32; off; off >>= 1) {
    p0 += __shfl_xor(p0, off);
    p1 += __shfl_xor(p1, off);
    p2 += __shfl_xor(p2, off);
  }
  __shared__ float red[4][3];
  int wv = tid >> 6, ln = tid & 63;
  if (ln == 0) { red[wv][0] = p0; red[wv][1] = p1; red[wv][2] = p2; }
  __syncthreads();
  if (tid < 3) {
    D[v * 4 + tid] = (red[0][tid] + red[1][tid]) + (red[2][tid] + red[3][tid]);
  }
}

// ---------------------------------------------------------------------------
// K2: EW[v,n] = sum_k Ebf[v,k]*Wb[n,k]   (gemm_bt, bf16 MFMA, f32 out, NO bias)
// m97 structure [guide §5 step 3]: global_load_lds dwordx4 staging, 128x128
// tile, BK=32, 4 waves each 64x64 (4x4 of 16x16x32). M=8192 -> grid (8,64),
// nwg=512 %8==0 -> bijective XCD-chunked swizzle (CPX=64).
// A-frag: A[m=lane&15][k=(lane>>4)*8+j]; C/D: col=lane&15, row=(lane>>4)*4+reg
// [guide §3, measured m89/m91/m97].
// ---------------------------------------------------------------------------
__global__ __launch_bounds__(256) void gemm_kernel(
    const ushort* __restrict__ A, const ushort* __restrict__ Wb,
    float* __restrict__ out) {
  __shared__ ushort As[128 * 32];
  __shared__ ushort Bs[128 * 32];
  int tid = threadIdx.x;
  int wave = tid >> 6, lane = tid & 63;

  // XCD-chunked swizzle (nwg = 512, divisible by 8 -> bijective; CPX = 64)
  int linear = (blockIdx.y << 3) | blockIdx.x;
  int swz = ((linear & 7) << 6) | (linear >> 3);
  int tileM = (swz >> 3) << 7;
  int tileN = (swz & 7) << 7;

  int wm = (wave >> 1) << 6;
  int wn = (wave & 1) << 6;

  f32x4 acc[4][4];
#pragma unroll
  for (int i = 0; i < 4; ++i)
#pragma unroll
    for (int j = 0; j < 4; ++j) acc[i][j] = (f32x4){0.f, 0.f, 0.f, 0.f};

  // staging addresses: wave w stages 32 rows of each operand as 2x1024B chunks
  int sr = lane >> 2;            // 0..15 row within chunk
  int sc = (lane & 3) << 3;      // elem col 0,8,16,24
  const ushort* Ap = A  + (size_t)(tileM + (wave << 5) + sr) * EDIM + sc;
  const ushort* Bp = Wb + (size_t)(tileN + (wave << 5) + sr) * EDIM + sc;
  ushort* aDst = &As[(wave << 1) * 512];   // 1024B chunk base (wave-uniform)
  ushort* bDst = &Bs[(wave << 1) * 512];

  int arow = lane & 15;
  int kq = (lane >> 4) << 3;

  for (int k0 = 0; k0 < EDIM; k0 += 32) {
    gld16(Ap + k0, aDst);
    gld16(Ap + (size_t)16 * EDIM + k0, aDst + 512);
    gld16(Bp + k0, bDst);
    gld16(Bp + (size_t)16 * EDIM + k0, bDst + 512);
    __syncthreads();   // compiler emits s_waitcnt vmcnt(0) lgkmcnt(0) first

    short8 af[4], bfv[4];
#pragma unroll
    for (int i = 0; i < 4; ++i) {
      af[i]  = *(const short8*)&As[(wm + i * 16 + arow) * 32 + kq];
      bfv[i] = *(const short8*)&Bs[(wn + i * 16 + arow) * 32 + kq];
    }
#pragma unroll
    for (int i = 0; i < 4; ++i)
#pragma unroll
      for (int j = 0; j < 4; ++j)
        acc[i][j] = __builtin_amdgcn_mfma_f32_16x16x32_bf16(af[i], bfv[j], acc[i][j], 0, 0, 0);
    __syncthreads();
  }

  int col0 = lane & 15, rq = (lane >> 4) << 2;
#pragma unroll
  for (int j = 0; j < 4; ++j) {
    int col = tileN + wn + j * 16 + col0;
#pragma unroll
    for (int i = 0; i < 4; ++i) {
      int row = tileM + wm + i * 16 + rq;
#pragma unroll
      for (int r = 0; r < 4; ++r)
        out[(size_t)(row + r) * EDIM + col] = acc[i][j][r];   // f32 store
    }
  }
}

// ---------------------------------------------------------------------------
// K3: final fused kernel, 8 TOKENS PER BLOCK (window overlap exploitation):
// consecutive tokens share 2/3 gather rows -> 10 row-loads instead of 24
// (gather traffic 384 -> 160 MB). All window scalars (idx, s_c) depend only
// on blockIdx -> SGPRs. One barrier for all 8 LN reductions.
// Blocks never straddle sequences (TDIM % 8 == 0), so only the t0==0 block
// of each sequence has boundary tokens (t=0: s0=s1=0; t=1: s0=0).
//   y_j = s0_j*r[j] + s1_j*r[j+1] + s2_j*r[j+2] + bias;  out = swish(LN(y)).
// ---------------------------------------------------------------------------
__global__ __launch_bounds__(256) void final_kernel(
    const int* __restrict__ tokens, const float* __restrict__ EW,
    const float* __restrict__ D, const float* __restrict__ bias,
    const float* __restrict__ g, const float* __restrict__ bta,
    float* __restrict__ out) {
  int m0 = blockIdx.x << 3;
  int t0 = m0 & (TDIM - 1);
  int tid = threadIdx.x;
  int e4 = tid << 2;

  // uniform (SGPR) window data
  int idx[10];
#pragma unroll
  for (int j = 0; j < 10; ++j) {
    int mm = m0 - 2 + j;
    idx[j] = tokens[mm < 0 ? 0 : mm];
  }
  const float inv = 1.0f / 24.0f;
  float s0[8], s1[8], s2[8];
#pragma unroll
  for (int j = 0; j < 8; ++j) {
    int t = t0 + j;
    s2[j] = D[idx[j + 2] * 4 + 2] * inv;
    s1[j] = (t >= 1) ? D[idx[j + 1] * 4 + 1] * inv : 0.f;
    s0[j] = (t >= 2) ? D[idx[j] * 4 + 0] * inv : 0.f;
  }

  // gather the 10 distinct window rows (per-thread float4 slices)
  float4 r[10];
#pragma unroll
  for (int j = 0; j < 10; ++j)
    r[j] = *(const float4*)&EW[(size_t)idx[j] * EDIM + e4];

  float4 bb = *(const float4*)&bias[e4];
  float4 y[8];
  float sred[8], qred[8];
#pragma unroll
  for (int j = 0; j < 8; ++j) {
    float4 v;
    v.x = s0[j] * r[j].x + s1[j] * r[j + 1].x + s2[j] * r[j + 2].x + bb.x;
    v.y = s0[j] * r[j].y + s1[j] * r[j + 1].y + s2[j] * r[j + 2].y + bb.y;
    v.z = s0[j] * r[j].z + s1[j] * r[j + 1].z + s2[j] * r[j + 2].z + bb.z;
    v.w = s0[j] * r[j].w + s1[j] * r[j + 1].w + s2[j] * r[j + 2].w + bb.w;
    y[j] = v;
    sred[j] = (v.x + v.y) + (v.z + v.w);
    qred[j] = (v.x * v.x + v.y * v.y) + (v.z * v.z + v.w * v.w);
  }

#pragma unroll
  for (int off = 32; off; off >>= 1) {
#pragma unroll
    for (int j = 0; j < 8; ++j) {
      sred[j] += __shfl_xor(sred[j], off);
      qred[j] += __shfl_xor(qred[j], off);
    }
  }
  __shared__ float red[4][8][2];
  int wv = tid >> 6, ln = tid & 63;
  if (ln == 0) {
#pragma unroll
    for (int j = 0; j < 8; ++j) {
      red[wv][j][0] = sred[j];
      red[wv][j][1] = qred[j];
    }
  }
  __syncthreads();

  float4 gg = *(const float4*)&g[e4];
  float4 b2 = *(const float4*)&bta[e4];
#pragma unroll
  for (int j = 0; j < 8; ++j) {
    float S = (red[0][j][0] + red[1][j][0]) + (red[2][j][0] + red[3][j][0]);
    float Q = (red[0][j][1] + red[1][j][1]) + (red[2][j][1] + red[3][j][1]);
    float mu = S * (1.0f / EDIM);
    float var = Q * (1.0f / EDIM) - mu * mu;
    float rs = rsqrtf(var + 1e-5f);
    float x0 = (y[j].x - mu) * rs * gg.x + b2.x;
    float x1 = (y[j].y - mu) * rs * gg.y + b2.y;
    float x2 = (y[j].z - mu) * rs * gg.z + b2.z;
    float x3 = (y[j].w - mu) * rs * gg.w + b2.w;
    float4 o;
    o.x = x0 / (1.f + expf(-x0));
    o.y = x1 / (1.f + expf(-x1));
    o.z = x2 / (1.f + expf(-x2));
    o.w = x3 / (1.f + expf(-x3));
    *(float4*)&out[(size_t)(m0 + j) * EDIM + e4] = o;
  }
}

// ---------------------------------------------------------------------------
// Buffer plan (ws usage < 51 MiB):
//   ws[ 0M : 16M)        Ebf   bf16 embed, 8192x1024 (dcvt -> gemm)
//   ws[16M : 48M)        EW    f32 embed@W^T, 8192x1024 (gemm -> final)
//   ws[48M : 50M)        Wb    bf16 ffn_w (prep -> gemm)
//   ws[50M : 50M+12K)    Psum  (prep -> dcvt)
//   ws[50M+16K : +128K)  D     f32 [8192][4] (dcvt -> final)
// OUTPUT IS F32 (reference output dtype = float32).
// ---------------------------------------------------------------------------
extern "C" void kernel_launch(void* const* d_in, const int* in_sizes, int n_in,
                              void* d_out, int out_size, void* d_ws, size_t ws_size,
                              hipStream_t stream) {
  const int*   tokens = (const int*)d_in[0];
  const float* embed  = (const float*)d_in[1];
  const float* pos_w  = (const float*)d_in[2];
  const float* ffn_w  = (const float*)d_in[3];
  const float* ffn_b  = (const float*)d_in[4];
  const float* ln_g   = (const float*)d_in[5];
  const float* ln_b   = (const float*)d_in[6];

  char* ws = (char*)d_ws;
  const size_t MB = 1024 * 1024;
  ushort* Ebf  = (ushort*)ws;                          // 16 MiB
  float*  EW   = (float*)(ws + 16 * MB);               // 32 MiB
  ushort* Wb   = (ushort*)(ws + 48 * MB);              // 2 MiB
  float*  Psum = (float*)(ws + 50 * MB);               // 12 KiB
  float*  D    = (float*)(ws + 50 * MB + 16 * 1024);   // 128 KiB
  float*  outp = (float*)d_out;                        // f32 output

  prep_kernel<<<1036, 256, 0, stream>>>(pos_w, ffn_w, Psum, Wb);
  dcvt_kernel<<<VCAP, 256, 0, stream>>>(embed, Psum, Ebf, D);
  dim3 g2(8, 64);
  gemm_kernel<<<g2, 256, 0, stream>>>(Ebf, Wb, EW);
  final_kernel<<<MTOT / 8, 256, 0, stream>>>(tokens, EW, D, ffn_b, ln_g, ln_b, outp);
}